// Round 17
// baseline (383.709 us; speedup 1.0000x reference)
//
#include <hip/hip_runtime.h>

// Problem constants
constexpr int Bb  = 16;
constexpr int Dd  = 128;
constexpr int Tt  = 2048;
constexpr int NQn = 8;
constexpr int CSc = 1024;

constexpr int TB  = 64;    // t per block (2 tiles x 32, shared by all 4 waves)
constexpr int CHH = 8192;  // _Float16 per 32-code chunk (16 KB)

typedef _Float16 half8 __attribute__((ext_vector_type(8)));
typedef __attribute__((ext_vector_type(4)))  float f32x4;
typedef __attribute__((ext_vector_type(16))) float f32x16;

// ---- scaled f16 2-plane split: x ~= H + M'*2^-12 (~22 mantissa bits) ----
__device__ inline void fsplit(float xv, _Float16& h, _Float16& m) {
    _Float16 hh = (__builtin_fabsf(xv) < 6.103515625e-05f) ? (_Float16)0.0f
                                                           : (_Float16)xv;
    float e = xv - (float)hh;
    h = hh;
    m = (_Float16)(e * 4096.0f);
}
__device__ inline float frec(_Float16 h, _Float16 m) {
    return fmaf((float)m, 2.44140625e-4f, (float)h);   // exact in fp32
}

#define MFMAH(A, B, C) __builtin_amdgcn_mfma_f32_32x32x16_f16(A, B, C, 0, 0, 0)

// ---------------------------------------------------------------------------
// Kernel 0: split codebook fp32 -> 2 f16 planes (H, M'), fragment-ordered per
// 32-code chunk for mfma_32x32x16 (layout identical to rounds 9-16).
// cn stores 0.5*||c||^2 (pre-halved for dist' = cn/2 - dot).
// ---------------------------------------------------------------------------
__global__ __launch_bounds__(64) void split_kernel(const float* __restrict__ cb,
                                                   _Float16* __restrict__ cbS,
                                                   float* __restrict__ cn) {
    const int c     = blockIdx.x * 64 + threadIdx.x;  // global code id
    const int chunk = c >> 5;
    const int c31   = c & 31;
    const float* p  = cb + (size_t)c * Dd;
    const size_t base = (size_t)chunk * CHH;

    float s0 = 0.f, s1 = 0.f, s2 = 0.f, s3 = 0.f;
#pragma unroll
    for (int ks = 0; ks < 8; ++ks) {
#pragma unroll
        for (int hi2 = 0; hi2 < 2; ++hi2) {
            const int lanew = hi2 * 32 + c31;
            half8 h8, m8;
#pragma unroll
            for (int jj = 0; jj < 8; jj += 4) {
                float4 v = *(const float4*)(p + ks * 16 + hi2 * 8 + jj);
                s0 = fmaf(v.x, v.x, s0);
                s1 = fmaf(v.y, v.y, s1);
                s2 = fmaf(v.z, v.z, s2);
                s3 = fmaf(v.w, v.w, s3);
                _Float16 hh, mm;
                fsplit(v.x, hh, mm); h8[jj + 0] = hh; m8[jj + 0] = mm;
                fsplit(v.y, hh, mm); h8[jj + 1] = hh; m8[jj + 1] = mm;
                fsplit(v.z, hh, mm); h8[jj + 2] = hh; m8[jj + 2] = mm;
                fsplit(v.w, hh, mm); h8[jj + 3] = hh; m8[jj + 3] = mm;
            }
            *(half8*)&cbS[base + (size_t)((0 * 8 + ks) * 64 + lanew) * 8] = h8;
            *(half8*)&cbS[base + (size_t)((8 + ks) * 64 + lanew) * 8]     = m8;
        }
    }
    cn[c] = 0.5f * ((s0 + s1) + (s2 + s3));   // pre-halved
}

// ---------------------------------------------------------------------------
// Kernel 1: MFMA RVQ, global-A, barrier-free scan, 2 B-tiles per wave.
// 256 threads = 4 waves = 4 codebook quarters; all waves share the block's
// 64 t (2 tiles of 32). A-fragments stream L2->VGPR in 4-record groups; no
// LDS/barriers in the scan loop. launch_bounds(256,2): total regs/wave <=256
// -> 2 waves/SIMD from TWO independent blocks (grid 512 = 2 blocks/CU).
// Numerics identical to rounds 9-16 (scaled-f16 split; dist' = cn/2 - dot).
// ---------------------------------------------------------------------------
__global__ __launch_bounds__(256, 2) void rvq_mfma(const float* __restrict__ x,
                                                   const float* __restrict__ cb,
                                                   const _Float16* __restrict__ cbS,
                                                   const float* __restrict__ cn_g,
                                                   float* __restrict__ out,
                                                   float* __restrict__ part) {
    __shared__ float s_best[4][2][32];   // [quarter][tile][col]
    __shared__ int   s_idx[4][2][32];

    const int tid  = threadIdx.x;
    const int lane = tid & 63;
    const int qd   = __builtin_amdgcn_readfirstlane(tid >> 6);  // quarter 0..3
    const int l31  = lane & 31;       // t within tile / C-D column
    const int hi   = lane >> 5;       // k-subgroup 0..1

    const int t0  = blockIdx.x * TB;
    const int b   = t0 >> 11;
    const int tb0 = t0 & (Tt - 1);
    const int tg0 = tb0 + l31;        // tile A
    const int tg1 = tg0 + 32;         // tile B
    const size_t xbase = (size_t)b * Dd * Tt;

    // ---- residual state: 2 f16 planes x 2 tiles (128 VGPR) ----
    half8 Bh0[8], Bm0[8], Bh1[8], Bm1[8];
#pragma unroll
    for (int ks = 0; ks < 8; ++ks) {
        half8 h80, m80, h81, m81;
#pragma unroll
        for (int j = 0; j < 8; ++j) {
            const size_t doff = (size_t)(ks * 16 + hi * 8 + j) * Tt;
            _Float16 hh, mm;
            fsplit(x[xbase + doff + tg0], hh, mm); h80[j] = hh; m80[j] = mm;
            fsplit(x[xbase + doff + tg1], hh, mm); h81[j] = hh; m81[j] = mm;
        }
        Bh0[ks] = h80; Bm0[ks] = m80;
        Bh1[ks] = h81; Bm1[ks] = m81;
    }

    float loss_acc = 0.f;

#pragma unroll 1
    for (int q = 0; q < NQn; ++q) {
        // this wave's quarter: 8 chunks of 32 codes, fragment-ordered
        const _Float16* gq  = cbS + (size_t)(q * 32 + qd * 8) * CHH;
        const float*    cnq = cn_g + (size_t)q * CSc + qd * 256;   // 0.5*||c||^2

        // 4-record A group loader (records rbase..rbase+3 of chunk ct)
        auto LOADG = [&](half8* dst, int ct, int rbase) {
            const _Float16* g = gq + (size_t)ct * CHH;
#pragma unroll
            for (int i = 0; i < 4; ++i)
                dst[i] = *(const half8*)&g[(size_t)((rbase + i) * 64 + lane) * 8];
        };

        half8 Qa[4], Pa[4];          // two A groups in flight (32 VGPR)
        LOADG(Qa, 0, 0);             // prologue: H-plane, half 0, chunk 0

        float best0 = 3.4e38f, best1 = 3.4e38f;
        int   bidx0 = 0,       bidx1 = 0;

#pragma unroll 1
        for (int ct = 0; ct < 8; ++ct) {
            f32x16 aA0 = {0.f,0.f,0.f,0.f,0.f,0.f,0.f,0.f,
                          0.f,0.f,0.f,0.f,0.f,0.f,0.f,0.f};
            f32x16 aB0 = aA0, aA1 = aA0, aB1 = aA0;

            // cn for blocks 0,1 (consumed at eval, far away)
            f32x4 cnb0 = *(const f32x4*)&cnq[ct * 32 + 0 * 8 + hi * 4];
            f32x4 cnb1 = *(const f32x4*)&cnq[ct * 32 + 1 * 8 + hi * 4];

            LOADG(Pa, ct, 8);                 // M-plane, half 0
            __builtin_amdgcn_s_setprio(1);
#pragma unroll
            for (int i = 0; i < 4; ++i) {     // H-block, ks = i
                aA0 = MFMAH(Qa[i], Bh0[i], aA0);
                aA1 = MFMAH(Qa[i], Bh1[i], aA1);
                aB0 = MFMAH(Qa[i], Bm0[i], aB0);
                aB1 = MFMAH(Qa[i], Bm1[i], aB1);
            }
            __builtin_amdgcn_s_setprio(0);

            LOADG(Qa, ct, 4);                 // H-plane, half 1
            __builtin_amdgcn_s_setprio(1);
#pragma unroll
            for (int i = 0; i < 4; ++i) {     // M-block, ks = i
                aB0 = MFMAH(Pa[i], Bh0[i], aB0);
                aB1 = MFMAH(Pa[i], Bh1[i], aB1);
            }
            __builtin_amdgcn_s_setprio(0);

            f32x4 cnb2 = *(const f32x4*)&cnq[ct * 32 + 2 * 8 + hi * 4];
            f32x4 cnb3 = *(const f32x4*)&cnq[ct * 32 + 3 * 8 + hi * 4];

            LOADG(Pa, ct, 12);                // M-plane, half 1
            __builtin_amdgcn_s_setprio(1);
#pragma unroll
            for (int i = 0; i < 4; ++i) {     // H-block, ks = 4+i
                aA0 = MFMAH(Qa[i], Bh0[4 + i], aA0);
                aA1 = MFMAH(Qa[i], Bh1[4 + i], aA1);
                aB0 = MFMAH(Qa[i], Bm0[4 + i], aB0);
                aB1 = MFMAH(Qa[i], Bm1[4 + i], aB1);
            }
            __builtin_amdgcn_s_setprio(0);

            if (ct < 7) LOADG(Qa, ct + 1, 0); // next chunk H-plane, half 0
            __builtin_amdgcn_s_setprio(1);
#pragma unroll
            for (int i = 0; i < 4; ++i) {     // M-block, ks = 4+i
                aB0 = MFMAH(Pa[i], Bh0[4 + i], aB0);
                aB1 = MFMAH(Pa[i], Bh1[4 + i], aB1);
            }
            __builtin_amdgcn_s_setprio(0);

            // eval 16 candidates per tile (dist' = cn/2 - dot)
            const int cb0 = qd * 256 + ct * 32;
#pragma unroll
            for (int blk = 0; blk < 4; ++blk) {
                f32x4 ch4 = (blk == 0) ? cnb0 : (blk == 1) ? cnb1
                          : (blk == 2) ? cnb2 : cnb3;
#pragma unroll
                for (int e = 0; e < 4; ++e) {
                    const int i   = blk * 4 + e;
                    const int cid = cb0 + blk * 8 + hi * 4 + e;
                    float d0 = ch4[e] - fmaf(aB0[i], 2.44140625e-4f, aA0[i]);
                    float d1 = ch4[e] - fmaf(aB1[i], 2.44140625e-4f, aA1[i]);
                    if (d0 < best0) { best0 = d0; bidx0 = cid; }   // strict <
                    if (d1 < best1) { best1 = d1; bidx1 = cid; }
                }
            }
        }

        // ---- argmin: combine two k-subgroups (same t), lexicographic ----
        {
            float ob = __shfl_xor(best0, 32, 64);
            int   oi = __shfl_xor(bidx0, 32, 64);
            if (ob < best0 || (ob == best0 && oi < bidx0)) { best0 = ob; bidx0 = oi; }
            ob = __shfl_xor(best1, 32, 64);
            oi = __shfl_xor(bidx1, 32, 64);
            if (ob < best1 || (ob == best1 && oi < bidx1)) { best1 = ob; bidx1 = oi; }
        }
        if (hi == 0) {
            s_best[qd][0][l31] = best0; s_idx[qd][0][l31] = bidx0;
            s_best[qd][1][l31] = best1; s_idx[qd][1][l31] = bidx1;
        }
        __syncthreads();
        // combine the 4 quarters, ascending order (lowest index wins ties)
        float gb0 = s_best[0][0][l31]; int gi0 = s_idx[0][0][l31];
        float gb1 = s_best[0][1][l31]; int gi1 = s_idx[0][1][l31];
#pragma unroll
        for (int q2 = 1; q2 < 4; ++q2) {
            float ob0 = s_best[q2][0][l31]; int oi0 = s_idx[q2][0][l31];
            float ob1 = s_best[q2][1][l31]; int oi1 = s_idx[q2][1][l31];
            if (ob0 < gb0 || (ob0 == gb0 && oi0 < gi0)) { gb0 = ob0; gi0 = oi0; }
            if (ob1 < gb1 || (ob1 == gb1 && oi1 < gi1)) { gb1 = ob1; gi1 = oi1; }
        }
        __syncthreads();   // protect s_best/s_idx reuse next quantizer

        // ---- residual update both tiles (verbatim round-16 numerics) ----
        float rnn0, rnn1;
        {
            const float* cp = cb + ((size_t)q * CSc + gi0) * Dd + hi * 8;
            float q0 = 0.f, q1 = 0.f, q2 = 0.f, q3 = 0.f;
#pragma unroll
            for (int ks = 0; ks < 8; ++ks) {
                f32x4 ca  = *(const f32x4*)(cp + ks * 16);
                f32x4 cb4 = *(const f32x4*)(cp + ks * 16 + 4);
                half8 h8 = Bh0[ks], m8 = Bm0[ks];
                half8 nh, nm;
#pragma unroll
                for (int j = 0; j < 8; ++j) {
                    float cj = (j < 4) ? ca[j] : cb4[j - 4];
                    float nv = frec(h8[j], m8[j]) - cj;
                    if ((j & 3) == 0)      q0 = fmaf(nv, nv, q0);
                    else if ((j & 3) == 1) q1 = fmaf(nv, nv, q1);
                    else if ((j & 3) == 2) q2 = fmaf(nv, nv, q2);
                    else                   q3 = fmaf(nv, nv, q3);
                    _Float16 hh, mm;
                    fsplit(nv, hh, mm);
                    nh[j] = hh; nm[j] = mm;
                }
                Bh0[ks] = nh; Bm0[ks] = nm;
            }
            rnn0 = (q0 + q1) + (q2 + q3);
            rnn0 += __shfl_xor(rnn0, 32, 64);
        }
        {
            const float* cp = cb + ((size_t)q * CSc + gi1) * Dd + hi * 8;
            float q0 = 0.f, q1 = 0.f, q2 = 0.f, q3 = 0.f;
#pragma unroll
            for (int ks = 0; ks < 8; ++ks) {
                f32x4 ca  = *(const f32x4*)(cp + ks * 16);
                f32x4 cb4 = *(const f32x4*)(cp + ks * 16 + 4);
                half8 h8 = Bh1[ks], m8 = Bm1[ks];
                half8 nh, nm;
#pragma unroll
                for (int j = 0; j < 8; ++j) {
                    float cj = (j < 4) ? ca[j] : cb4[j - 4];
                    float nv = frec(h8[j], m8[j]) - cj;
                    if ((j & 3) == 0)      q0 = fmaf(nv, nv, q0);
                    else if ((j & 3) == 1) q1 = fmaf(nv, nv, q1);
                    else if ((j & 3) == 2) q2 = fmaf(nv, nv, q2);
                    else                   q3 = fmaf(nv, nv, q3);
                    _Float16 hh, mm;
                    fsplit(nv, hh, mm);
                    nh[j] = hh; nm[j] = mm;
                }
                Bh1[ks] = nh; Bm1[ks] = nm;
            }
            rnn1 = (q0 + q1) + (q2 + q3);
            rnn1 += __shfl_xor(rnn1, 32, 64);
        }
        if (qd == 0) loss_acc += rnn0 + rnn1;   // both hi lanes count -> x2
    }

    // ---- epilogue: q_sum = x0 - r_final (qd==0 wave; state identical) ----
    if (qd == 0) {
#pragma unroll
        for (int ks = 0; ks < 8; ++ks) {
            half8 h80 = Bh0[ks], m80 = Bm0[ks];
            half8 h81 = Bh1[ks], m81 = Bm1[ks];
#pragma unroll
            for (int j = 0; j < 8; ++j) {
                const size_t doff = xbase + (size_t)(ks * 16 + hi * 8 + j) * Tt;
                out[doff + tg0] = x[doff + tg0] - frec(h80[j], m80[j]);
                out[doff + tg1] = x[doff + tg1] - frec(h81[j], m81[j]);
            }
        }
        float ls = loss_acc;
#pragma unroll
        for (int off = 32; off > 0; off >>= 1) ls += __shfl_down(ls, off, 64);
        if (lane == 0) part[blockIdx.x] = 0.5f * ls;
    }
}

// ---------------------------------------------------------------------------
// Kernel 2: deterministic loss reduction (32 block-partials per batch element)
// ---------------------------------------------------------------------------
__global__ __launch_bounds__(64) void loss_kernel(const float* __restrict__ part,
                                                  float* __restrict__ out_loss) {
    int b = threadIdx.x;
    if (b < Bb) {
        float s = 0.f;
        const int ppb = Tt / TB;  // 32
        for (int k = 0; k < ppb; ++k) s += part[b * ppb + k];
        out_loss[b] = s * (1.0f / ((float)Dd * (float)Tt));
    }
}

// ---------------------------------------------------------------------------
extern "C" void kernel_launch(void* const* d_in, const int* in_sizes, int n_in,
                              void* d_out, int out_size, void* d_ws, size_t ws_size,
                              hipStream_t stream) {
    const float* x  = (const float*)d_in[0];   // [B, D, T]
    const float* cb = (const float*)d_in[1];   // [NQ, CS, D]
    float* out = (float*)d_out;                // [B*D*T] q_sum ++ [B] loss_sum

    // workspace: cn(half)[8192] f32 | part[512] f32 | cbS 2-plane f16 (4 MB)
    float*    cn   = (float*)d_ws;
    float*    part = cn + NQn * CSc;
    _Float16* cbS  = (_Float16*)(part + 512);

    split_kernel<<<(NQn * CSc) / 64, 64, 0, stream>>>(cb, cbS, cn);

    const int nblocks = (Bb * Tt) / TB;  // 512
    rvq_mfma<<<nblocks, 256, 0, stream>>>(x, cb, cbS, cn, out, part);

    loss_kernel<<<1, 64, 0, stream>>>(part, out + (size_t)Bb * Dd * Tt);
}

// Round 18
// 272.886 us; speedup vs baseline: 1.4061x; 1.4061x over previous
//
#include <hip/hip_runtime.h>

// Problem constants
constexpr int Bb  = 16;
constexpr int Dd  = 128;
constexpr int Tt  = 2048;
constexpr int NQn = 8;
constexpr int CSc = 1024;

constexpr int TB   = 128;   // t per block
constexpr int NCHQ = 16;    // 32-code chunks per half per quantizer
constexpr int CHH  = 8192;  // _Float16 per chunk: 32 codes * 128 d * 2 planes (16 KB)

typedef _Float16 half8 __attribute__((ext_vector_type(8)));
typedef __attribute__((ext_vector_type(4)))  float f32x4;
typedef __attribute__((ext_vector_type(16))) float f32x16;

// ---- scaled f16 2-plane split: x ~= H + M'*2^-12 (~22 mantissa bits) ----
__device__ inline void fsplit(float xv, _Float16& h, _Float16& m) {
    _Float16 hh = (__builtin_fabsf(xv) < 6.103515625e-05f) ? (_Float16)0.0f
                                                           : (_Float16)xv;
    float e = xv - (float)hh;
    h = hh;
    m = (_Float16)(e * 4096.0f);
}
__device__ inline float frec(_Float16 h, _Float16 m) {
    return fmaf((float)m, 2.44140625e-4f, (float)h);   // exact in fp32
}

// async global->LDS, 16 B/lane (LDS dest = wave-uniform base + lane*16)
__device__ inline void gload_lds16(const _Float16* g, _Float16* l) {
    __builtin_amdgcn_global_load_lds(
        (const __attribute__((address_space(1))) void*)g,
        (__attribute__((address_space(3))) void*)l, 16, 0, 0);
}

#define MFMAH(A, B, C) __builtin_amdgcn_mfma_f32_32x32x16_f16(A, B, C, 0, 0, 0)

// ---------------------------------------------------------------------------
// Kernel 0: split codebook fp32 -> 2 f16 planes (H, M'), fragment-ordered per
// 32-code chunk for mfma_32x32x16 (layout identical to rounds 9-17).
// cn stores 0.5*||c||^2 (pre-halved for dist' = cn/2 - dot).
// ---------------------------------------------------------------------------
__global__ __launch_bounds__(64) void split_kernel(const float* __restrict__ cb,
                                                   _Float16* __restrict__ cbS,
                                                   float* __restrict__ cn) {
    const int c     = blockIdx.x * 64 + threadIdx.x;  // global code id
    const int chunk = c >> 5;
    const int c31   = c & 31;
    const float* p  = cb + (size_t)c * Dd;
    const size_t base = (size_t)chunk * CHH;

    float s0 = 0.f, s1 = 0.f, s2 = 0.f, s3 = 0.f;
#pragma unroll
    for (int ks = 0; ks < 8; ++ks) {
#pragma unroll
        for (int hi2 = 0; hi2 < 2; ++hi2) {
            const int lanew = hi2 * 32 + c31;
            half8 h8, m8;
#pragma unroll
            for (int jj = 0; jj < 8; jj += 4) {
                float4 v = *(const float4*)(p + ks * 16 + hi2 * 8 + jj);
                s0 = fmaf(v.x, v.x, s0);
                s1 = fmaf(v.y, v.y, s1);
                s2 = fmaf(v.z, v.z, s2);
                s3 = fmaf(v.w, v.w, s3);
                _Float16 hh, mm;
                fsplit(v.x, hh, mm); h8[jj + 0] = hh; m8[jj + 0] = mm;
                fsplit(v.y, hh, mm); h8[jj + 1] = hh; m8[jj + 1] = mm;
                fsplit(v.z, hh, mm); h8[jj + 2] = hh; m8[jj + 2] = mm;
                fsplit(v.w, hh, mm); h8[jj + 3] = hh; m8[jj + 3] = mm;
            }
            *(half8*)&cbS[base + (size_t)((0 * 8 + ks) * 64 + lanew) * 8] = h8;
            *(half8*)&cbS[base + (size_t)((8 + ks) * 64 + lanew) * 8]     = m8;
        }
    }
    cn[c] = 0.5f * ((s0 + s1) + (s2 + s3));   // pre-halved
}

// ---------------------------------------------------------------------------
// Kernel 1: MFMA RVQ (round-9 structure, spill-free). 512 threads = 8 waves =
// 4 t-tiles(32 t) x 2 code-halves. Residual = 2 f16 planes in registers.
// Codebook chunks staged global->LDS via 3-buffer ring + counted vmcnt(4).
// NEW vs r9: chunk A processed in two 4-ks half-passes (A live 32 regs, was
// 64) and single merged cross-term acc chain (32 regs, was 48) -> total live
// ~120 <= 128: no scratch spill. dist' = cn/2 - dot (r11-validated).
// ---------------------------------------------------------------------------
__global__ __launch_bounds__(512) void rvq_mfma(const float* __restrict__ x,
                                                const float* __restrict__ cb,
                                                const _Float16* __restrict__ cbS,
                                                const float* __restrict__ cn_g,
                                                float* __restrict__ out,
                                                float* __restrict__ part) {
    __shared__ __align__(16) _Float16 sA[3][2][CHH];   // 96 KB ring
    __shared__ __align__(16) float    cn_lds[CSc];     // 0.5*||c||^2, 4 KB
    __shared__ float s_best[8][32];
    __shared__ int   s_idx[8][32];
    __shared__ float s_red[4];

    const int tid  = threadIdx.x;
    const int lane = tid & 63;
    const int w    = __builtin_amdgcn_readfirstlane(tid >> 6);
    const int tt   = w >> 1;          // t-tile 0..3
    const int h    = w & 1;           // code half
    const int l31  = lane & 31;       // t within tile / C-D column
    const int hi   = lane >> 5;       // k-subgroup 0..1

    const int t0  = blockIdx.x * TB;
    const int b   = t0 >> 11;
    const int tb0 = t0 & (Tt - 1);
    const int tg  = tb0 + tt * 32 + l31;
    const size_t xbase = (size_t)b * Dd * Tt;

    // ---- residual state: 2 f16 planes; lane owns dims ks*16+hi*8+j of t=tg
    half8 Bh[8], Bm[8];
#pragma unroll
    for (int ks = 0; ks < 8; ++ks) {
        half8 h8, m8;
#pragma unroll
        for (int j = 0; j < 8; ++j) {
            _Float16 hh, mm;
            fsplit(x[xbase + (size_t)(ks * 16 + hi * 8 + j) * Tt + tg], hh, mm);
            h8[j] = hh; m8[j] = mm;
        }
        Bh[ks] = h8; Bm[ks] = m8;
    }

    float loss_acc = 0.f;

#pragma unroll 1
    for (int q = 0; q < NQn; ++q) {
        // stage 0.5*||c||^2 for this quantizer (512 threads x 8 B)
        *(float2*)&cn_lds[tid * 2] = *(const float2*)&cn_g[(size_t)q * CSc + tid * 2];

        // staging: wave w copies 4 KB of its half's 16-KB chunk
        auto STAGE = [&](int ct, int bb) {
            const int gc = q * 32 + h * 16 + ct;
            const _Float16* g = cbS + (size_t)gc * CHH + tt * 2048 + lane * 8;
            _Float16* dl = &sA[bb][h][tt * 2048];
#pragma unroll
            for (int i = 0; i < 4; ++i) gload_lds16(g + i * 512, dl + i * 512);
        };

        // prologue: chunks 0,1 -> bufs 0,1; wait chunk 0 (chunk 1 in flight)
        STAGE(0, 0);
        STAGE(1, 1);
        asm volatile("s_waitcnt vmcnt(4) lgkmcnt(0)" ::: "memory");
        __builtin_amdgcn_s_barrier();
        asm volatile("" ::: "memory");

        float best = 3.4e38f;
        int   bidx = 0;
        int   buf  = 0;

#pragma unroll 1
        for (int ct = 0; ct < NCHQ; ++ct) {
            const bool iss = (ct + 2) < NCHQ;
            if (iss) {                       // 2-deep prefetch into buf+2 (mod 3)
                int b2 = buf - 1; if (b2 < 0) b2 = 2;
                STAGE(ct + 2, b2);
            }

            // chunk compute: two 4-ks half-passes, 32 A-regs live, 2 acc chains
            const _Float16* ab = &sA[buf][h][0];
            f32x16 aA = {0.f,0.f,0.f,0.f,0.f,0.f,0.f,0.f,
                         0.f,0.f,0.f,0.f,0.f,0.f,0.f,0.f};
            f32x16 aB = aA;
#pragma unroll
            for (int hf = 0; hf < 2; ++hf) {
                half8 Ah[4], Am[4];
#pragma unroll
                for (int i = 0; i < 4; ++i) {
                    Ah[i] = *(const half8*)&ab[(size_t)((hf * 4 + i) * 64 + lane) * 8];
                    Am[i] = *(const half8*)&ab[(size_t)((8 + hf * 4 + i) * 64 + lane) * 8];
                }
                __builtin_amdgcn_s_setprio(1);
#pragma unroll
                for (int i = 0; i < 4; ++i) {
                    const int ks = hf * 4 + i;
                    aA = MFMAH(Ah[i], Bh[ks], aA);    // H_c * H_r
                    aB = MFMAH(Ah[i], Bm[ks], aB);    // H_c * M'_r (2^12-scaled)
                    aB = MFMAH(Am[i], Bh[ks], aB);    // M'_c * H_r (2^12-scaled)
                }
                __builtin_amdgcn_s_setprio(0);
            }

            // eval 16 candidates (dist' = cn/2 - dot; argmin-equivalent)
            const int cq = h * 512 + ct * 32;
#pragma unroll
            for (int blk = 0; blk < 4; ++blk) {
                f32x4 ch4 = *(const f32x4*)&cn_lds[cq + blk * 8 + hi * 4];
#pragma unroll
                for (int e = 0; e < 4; ++e) {
                    const int i = blk * 4 + e;
                    float dd = ch4[e] - fmaf(aB[i], 2.44140625e-4f, aA[i]);
                    // C/D: code = (reg&3)+8*(reg>>2)+4*hi, col = t (r7-verified)
                    int cid = cq + blk * 8 + hi * 4 + e;
                    if (dd < best) { best = dd; bidx = cid; }   // strict <
                }
            }

            // counted wait: the just-issued prefetch (4 loads) stays in flight
            if (iss) asm volatile("s_waitcnt vmcnt(4)" ::: "memory");
            else     asm volatile("s_waitcnt vmcnt(0)" ::: "memory");
            __builtin_amdgcn_s_barrier();
            asm volatile("" ::: "memory");

            ++buf; if (buf == 3) buf = 0;
        }

        // ---- argmin: combine two k-subgroups (same t), lexicographic ----
        {
            float ob = __shfl_xor(best, 32, 64);
            int   oi = __shfl_xor(bidx, 32, 64);
            if (ob < best || (ob == best && oi < bidx)) { best = ob; bidx = oi; }
        }
        if (hi == 0) { s_best[w][l31] = best; s_idx[w][l31] = bidx; }
        __syncthreads();
        // combine with partner half (lex -> lowest index wins ties)
        {
            float ob = s_best[w ^ 1][l31];
            int   oi = s_idx[w ^ 1][l31];
            if (ob < best || (ob == best && oi < bidx)) { best = ob; bidx = oi; }
        }
        const int g = bidx;

        // ---- residual update: reconstruct H+M'*2^-12, subtract fp32 code,
        //      re-split; accumulate loss = ||r_new||^2 (verbatim r9) ----
        {
            const float* cp = cb + ((size_t)q * CSc + g) * Dd + hi * 8;
            float q0 = 0.f, q1 = 0.f, q2 = 0.f, q3 = 0.f;
#pragma unroll
            for (int ks = 0; ks < 8; ++ks) {
                f32x4 ca  = *(const f32x4*)(cp + ks * 16);
                f32x4 cb4 = *(const f32x4*)(cp + ks * 16 + 4);
                half8 h8 = Bh[ks], m8 = Bm[ks];
                half8 nh, nm;
#pragma unroll
                for (int j = 0; j < 8; ++j) {
                    float cj = (j < 4) ? ca[j] : cb4[j - 4];
                    float nv = frec(h8[j], m8[j]) - cj;
                    if ((j & 3) == 0)      q0 = fmaf(nv, nv, q0);
                    else if ((j & 3) == 1) q1 = fmaf(nv, nv, q1);
                    else if ((j & 3) == 2) q2 = fmaf(nv, nv, q2);
                    else                   q3 = fmaf(nv, nv, q3);
                    _Float16 hh, mm;
                    fsplit(nv, hh, mm);
                    nh[j] = hh; nm[j] = mm;
                }
                Bh[ks] = nh; Bm[ks] = nm;
            }
            float rnn = (q0 + q1) + (q2 + q3);
            rnn += __shfl_xor(rnn, 32, 64);
            if (h == 0) loss_acc += rnn;    // both hi lanes count -> x2
        }
    }

    // ---- epilogue: q_sum = x0 - r_final (h==0 waves; state identical) ----
    if (h == 0) {
#pragma unroll
        for (int ks = 0; ks < 8; ++ks) {
            half8 h8 = Bh[ks], m8 = Bm[ks];
#pragma unroll
            for (int j = 0; j < 8; ++j) {
                size_t off = xbase + (size_t)(ks * 16 + hi * 8 + j) * Tt + tg;
                out[off] = x[off] - frec(h8[j], m8[j]);
            }
        }
        float ls = loss_acc;
#pragma unroll
        for (int off = 32; off > 0; off >>= 1) ls += __shfl_down(ls, off, 64);
        if (lane == 0) s_red[tt] = ls;
    }
    __syncthreads();
    if (tid == 0)
        part[blockIdx.x] = 0.5f * ((s_red[0] + s_red[1]) + (s_red[2] + s_red[3]));
}

// ---------------------------------------------------------------------------
// Kernel 2: deterministic loss reduction (16 block-partials per batch element)
// ---------------------------------------------------------------------------
__global__ __launch_bounds__(64) void loss_kernel(const float* __restrict__ part,
                                                  float* __restrict__ out_loss) {
    int b = threadIdx.x;
    if (b < Bb) {
        float s = 0.f;
        const int ppb = Tt / TB;  // 16
        for (int k = 0; k < ppb; ++k) s += part[b * ppb + k];
        out_loss[b] = s * (1.0f / ((float)Dd * (float)Tt));
    }
}

// ---------------------------------------------------------------------------
extern "C" void kernel_launch(void* const* d_in, const int* in_sizes, int n_in,
                              void* d_out, int out_size, void* d_ws, size_t ws_size,
                              hipStream_t stream) {
    const float* x  = (const float*)d_in[0];   // [B, D, T]
    const float* cb = (const float*)d_in[1];   // [NQ, CS, D]
    float* out = (float*)d_out;                // [B*D*T] q_sum ++ [B] loss_sum

    // workspace: cn(half)[8192] f32 | part[256] f32 | cbS 2-plane f16 (4 MB)
    float*    cn   = (float*)d_ws;
    float*    part = cn + NQn * CSc;
    _Float16* cbS  = (_Float16*)(part + 256);

    split_kernel<<<(NQn * CSc) / 64, 64, 0, stream>>>(cb, cbS, cn);

    const int nblocks = (Bb * Tt) / TB;  // 256
    rvq_mfma<<<nblocks, 512, 0, stream>>>(x, cb, cbS, cn, out, part);

    loss_kernel<<<1, 64, 0, stream>>>(part, out + (size_t)Bb * Dd * Tt);
}